// Round 4
// baseline (124.486 us; speedup 1.0000x reference)
//
#include <hip/hip_runtime.h>
#include <hip/hip_fp16.h>

#define T_TOTAL 262144
#define DD 128
#define HH 256

// ---- phase 1: coefficient GEMM ----
#define P1_BLOCKS 2048
#define TILE_T 16
#define TPB (T_TOTAL / TILE_T / P1_BLOCKS)   // 8 tiles per block
#define XPITCH 136                            // halves; 272 B row pitch -> 2-way max

// ---- phase 2: serial chain ----
#define P2_CHUNKS 2048
#define P2_L (T_TOTAL / P2_CHUNKS)   // 128
#define BURN 40

typedef _Float16 half8 __attribute__((ext_vector_type(8)));
typedef float f32x4 __attribute__((ext_vector_type(4)));

__device__ __forceinline__ float fast_tanh(float x) {
    float e = __expf(2.0f * x);
#if __has_builtin(__builtin_amdgcn_rcpf)
    float r = __builtin_amdgcn_rcpf(e + 1.0f);
#else
    float r = 1.0f / (e + 1.0f);
#endif
    return 1.0f - 2.0f * r;
}

template <int CTRL>
__device__ __forceinline__ float dpp_add(float x) {
    int t = __builtin_amdgcn_update_dpp(0, __float_as_int(x), CTRL, 0xf, 0xf, true);
    return x + __int_as_float(t);
}

// sum across the 16 lanes of each DPP row; lane (l&15)==15 holds the row sum
__device__ __forceinline__ float red16(float v) {
    v = dpp_add<0x111>(v);
    v = dpp_add<0x112>(v);
    v = dpp_add<0x114>(v);
    v = dpp_add<0x118>(v);
    return v;
}

__device__ __forceinline__ half8 cvt8(float4 a, float4 b) {
    half8 h;
    h[0] = (_Float16)a.x; h[1] = (_Float16)a.y;
    h[2] = (_Float16)a.z; h[3] = (_Float16)a.w;
    h[4] = (_Float16)b.x; h[5] = (_Float16)b.y;
    h[6] = (_Float16)b.z; h[7] = (_Float16)b.w;
    return h;
}

// Phase 1: per step t, cubic coefficients of u(z) = sum_j W2_j tanh(A[t][j] + wz_j z) + b2
//   c0 = sum W2 f + b2 ; c1 = sum W2 wz d ; c2 = -sum W2 wz^2 f d ;
//   c3 = sum W2 wz^3 d (f^2 - 1/3)     with f = tanh(A + b1), d = 1 - f^2.
__global__ __launch_bounds__(256, 4)
void coeff_kernel(const float* __restrict__ X, const float* __restrict__ W1,
                  const float* __restrict__ b1, const float* __restrict__ W2,
                  const float* __restrict__ b2, float4* __restrict__ cs)
{
    const int tid = threadIdx.x;
    const int wid = tid >> 6;         // wave owns j in [64*wid, 64*wid+64)
    const int l   = tid & 63;
    const int r16 = l & 15;
    const int g   = l >> 4;
    const int jb  = wid * 64;

    __shared__ __align__(16) _Float16 xs[2][TILE_T][XPITCH];  // 8704 B
    __shared__ float4 redbuf[2][4][TILE_T];                    // 2 KB

    // ---- permanent W fragments (B-operand): lane r16 <-> j, k = g*8 + ks*32 ----
    half8 wf[4][4];
    float b1j[4], q0[4], q1[4], q2n[4], q3[4];
    #pragma unroll
    for (int js = 0; js < 4; ++js) {
        const int j = jb + js * 16 + r16;
        const float* wr = W1 + j * (DD + 1);
        #pragma unroll
        for (int ks = 0; ks < 4; ++ks) {
            const float4 a = *(const float4*)(wr + g * 8 + ks * 32);
            const float4 b = *(const float4*)(wr + g * 8 + ks * 32 + 4);
            wf[js][ks] = cvt8(a, b);
        }
        b1j[js] = b1[j];
        const float wz = wr[DD];
        const float w2 = W2[j];
        q0[js]  = w2;
        q1[js]  = w2 * wz;
        q2n[js] = -w2 * wz * wz;
        q3[js]  = w2 * wz * wz * wz;
    }
    const float b2s = b2[0];

    const int t0 = blockIdx.x * (TPB * TILE_T);

    // ---- X staging: thread stages 8 contiguous halves of one row ----
    const int sr = tid >> 4;          // 0..15
    const int sc = (tid & 15) * 8;    // 0..120
    float4 sa, sb;
    auto ld_x = [&](int tt) {
        const float* p = X + (long long)(tt + sr) * DD + sc;
        sa = *(const float4*)(p);
        sb = *(const float4*)(p + 4);
    };
    auto st_x = [&](int buf) {
        *(half8*)&xs[buf][sr][sc] = cvt8(sa, sb);
    };

    ld_x(t0);
    st_x(0);

    for (int tile = 0; tile < TPB; ++tile) {
        const int tt = t0 + tile * TILE_T;
        __syncthreads();   // xs[tile&1] + redbuf[(tile-1)&1] visible

        // finalize previous tile's coefficients
        if (tile > 0 && tid < TILE_T) {
            const float4 a0 = redbuf[(tile - 1) & 1][0][tid];
            const float4 a1 = redbuf[(tile - 1) & 1][1][tid];
            const float4 a2 = redbuf[(tile - 1) & 1][2][tid];
            const float4 a3 = redbuf[(tile - 1) & 1][3][tid];
            float4 s;
            s.x = a0.x + a1.x + a2.x + a3.x + b2s;
            s.y = a0.y + a1.y + a2.y + a3.y;
            s.z = a0.z + a1.z + a2.z + a3.z;
            s.w = a0.w + a1.w + a2.w + a3.w;
            cs[tt - TILE_T + tid] = s;
        }

        if (tile + 1 < TPB) ld_x(tt + TILE_T);   // global prefetch (regs)

        // fragments from LDS
        half8 xf[4];
        #pragma unroll
        for (int ks = 0; ks < 4; ++ks)
            xf[ks] = *(const half8*)&xs[tile & 1][r16][ks * 32 + g * 8];

        f32x4 acc[4];
        #pragma unroll
        for (int js = 0; js < 4; ++js)
            acc[js] = f32x4{b1j[js], b1j[js], b1j[js], b1j[js]};
        #pragma unroll
        for (int js = 0; js < 4; ++js)
            #pragma unroll
            for (int ks = 0; ks < 4; ++ks)
                acc[js] = __builtin_amdgcn_mfma_f32_16x16x32_f16(
                    xf[ks], wf[js][ks], acc[js], 0, 0, 0);

        // postproc: element (t = tt + g*4 + r, j = jb + js*16 + r16)
        f32x4 c0 = {0,0,0,0}, c1 = {0,0,0,0}, c2 = {0,0,0,0}, c3 = {0,0,0,0};
        #pragma unroll
        for (int js = 0; js < 4; ++js) {
            #pragma unroll
            for (int r = 0; r < 4; ++r) {
                const float f  = fast_tanh(acc[js][r]);
                const float ff = f * f;
                const float d  = 1.0f - ff;
                const float fd = f * d;
                const float t3 = d * (ff - 0.3333333333f);
                c0[r] = fmaf(q0[js],  f,  c0[r]);
                c1[r] = fmaf(q1[js],  d,  c1[r]);
                c2[r] = fmaf(q2n[js], fd, c2[r]);
                c3[r] = fmaf(q3[js],  t3, c3[r]);
            }
        }
        #pragma unroll
        for (int r = 0; r < 4; ++r) {
            c0[r] = red16(c0[r]); c1[r] = red16(c1[r]);
            c2[r] = red16(c2[r]); c3[r] = red16(c3[r]);
        }
        if (r16 == 15) {
            #pragma unroll
            for (int r = 0; r < 4; ++r)
                redbuf[tile & 1][wid][g * 4 + r] =
                    make_float4(c0[r], c1[r], c2[r], c3[r]);
        }

        if (tile + 1 < TPB) st_x((tile + 1) & 1);   // LDS write for next tile
    }

    __syncthreads();
    if (tid < TILE_T) {
        const int last = TPB - 1;
        const float4 a0 = redbuf[last & 1][0][tid];
        const float4 a1 = redbuf[last & 1][1][tid];
        const float4 a2 = redbuf[last & 1][2][tid];
        const float4 a3 = redbuf[last & 1][3][tid];
        float4 s;
        s.x = a0.x + a1.x + a2.x + a3.x + b2s;
        s.y = a0.y + a1.y + a2.y + a3.y;
        s.z = a0.z + a1.z + a2.z + a3.z;
        s.w = a0.w + a1.w + a2.w + a3.w;
        cs[t0 + last * TILE_T + tid] = s;
    }
}

// Phase 2: burn-in + scalar cubic chain; z's buffered in LDS, stores vectorized.
__global__ __launch_bounds__(64)
void chain_kernel(const float4* __restrict__ cs, float* __restrict__ out)
{
    const int c   = blockIdx.x;
    const int tid = threadIdx.x;
    const int s0     = (c == 0) ? 0 : c * P2_L - BURN;
    const int t_end  = min((c + 1) * P2_L, T_TOTAL - 1);
    const int n      = t_end - s0;
    const int wstart = c * P2_L;
    const int skip   = wstart - s0;          // 0 or BURN

    __shared__ float4 cl[P2_L + BURN];
    __shared__ float  zb[P2_L + BURN];
    for (int i = tid; i < n; i += 64) cl[i] = cs[s0 + i];
    __syncthreads();

    float z = 0.0f;
    #pragma unroll 4
    for (int i = 0; i < n; ++i) {
        const float4 k = cl[i];
        const float u = fmaf(fmaf(fmaf(k.w, z, k.z), z, k.y), z, k.x);
        z = fast_tanh(u);
        if (tid == 0) zb[i] = z;
    }
    __syncthreads();

    if (c == 0 && tid == 0) out[0] = 0.0f;
    for (int i = tid; i + skip < n; i += 64)
        out[wstart + 1 + i] = zb[skip + i];
}

extern "C" void kernel_launch(void* const* d_in, const int* in_sizes, int n_in,
                              void* d_out, int out_size, void* d_ws, size_t ws_size,
                              hipStream_t stream) {
    const float* X  = (const float*)d_in[0];
    const float* W1 = (const float*)d_in[1];
    const float* b1 = (const float*)d_in[2];
    const float* W2 = (const float*)d_in[3];
    const float* b2 = (const float*)d_in[4];
    float* out = (float*)d_out;
    float4* cs = (float4*)d_ws;        // 262144 * 16 B = 4 MiB scratch
    (void)in_sizes; (void)n_in; (void)out_size; (void)ws_size;

    coeff_kernel<<<P1_BLOCKS, 256, 0, stream>>>(X, W1, b1, W2, b2, cs);
    chain_kernel<<<P2_CHUNKS, 64, 0, stream>>>(cs, out);
}

// Round 5
// 115.729 us; speedup vs baseline: 1.0757x; 1.0757x over previous
//
#include <hip/hip_runtime.h>
#include <hip/hip_fp16.h>

#define T_TOTAL 262144
#define DD 128
#define HH 256

// ---- phase 1: coefficient GEMM ----
#define P1_BLOCKS 2048
#define TILE_T 16
#define TPB (T_TOTAL / TILE_T / P1_BLOCKS)   // 8 tiles per block

// ---- phase 2: serial chain ----
#define P2_CHUNKS 2048
#define P2_L (T_TOTAL / P2_CHUNKS)   // 128
#define BURN 40

typedef _Float16 half8 __attribute__((ext_vector_type(8)));
typedef float f32x4 __attribute__((ext_vector_type(4)));

__device__ __forceinline__ float fast_tanh(float x) {
    float e = __expf(2.0f * x);
#if __has_builtin(__builtin_amdgcn_rcpf)
    float r = __builtin_amdgcn_rcpf(e + 1.0f);
#else
    float r = 1.0f / (e + 1.0f);
#endif
    return 1.0f - 2.0f * r;
}

template <int CTRL>
__device__ __forceinline__ float dpp_add(float x) {
    int t = __builtin_amdgcn_update_dpp(0, __float_as_int(x), CTRL, 0xf, 0xf, true);
    return x + __int_as_float(t);
}

// sum across the 16 lanes of each DPP row; lane (l&15)==15 holds the row sum
__device__ __forceinline__ float red16(float v) {
    v = dpp_add<0x111>(v);
    v = dpp_add<0x112>(v);
    v = dpp_add<0x114>(v);
    v = dpp_add<0x118>(v);
    return v;
}

__device__ __forceinline__ half8 cvt8(float4 a, float4 b) {
    half8 h;
    h[0] = (_Float16)a.x; h[1] = (_Float16)a.y;
    h[2] = (_Float16)a.z; h[3] = (_Float16)a.w;
    h[4] = (_Float16)b.x; h[5] = (_Float16)b.y;
    h[6] = (_Float16)b.z; h[7] = (_Float16)b.w;
    return h;
}

// Phase 1: per step t, cubic coefficients of u(z) = sum_j W2_j tanh(A[t][j] + wz_j z) + b2
//   c0 = sum W2 f + b2 ; c1 = sum W2 wz d ; c2 = -sum W2 wz^2 f d ;
//   c3 = sum W2 wz^3 d (f^2 - 1/3)     with f = tanh(A + b1), d = 1 - f^2.
__global__ __launch_bounds__(256, 2)
void coeff_kernel(const float* __restrict__ X, const float* __restrict__ W1,
                  const float* __restrict__ b1, const float* __restrict__ W2,
                  const float* __restrict__ b2, float4* __restrict__ cs)
{
    const int tid = threadIdx.x;
    const int wid = tid >> 6;         // wave owns j in [64*wid, 64*wid+64)
    const int l   = tid & 63;
    const int r16 = l & 15;
    const int g   = l >> 4;
    const int jb  = wid * 64;

    __shared__ float4 redbuf[2][4][TILE_T];   // double-buffered partials, 2 KB

    // ---- permanent W fragments (B-operand): lane r16 <-> j, k = g*8 + ks*32 ----
    half8 wf[4][4];
    float b1j[4], q0[4], q1[4], q2n[4], q3[4];
    #pragma unroll
    for (int js = 0; js < 4; ++js) {
        const int j = jb + js * 16 + r16;
        const float* wr = W1 + j * (DD + 1);
        #pragma unroll
        for (int ks = 0; ks < 4; ++ks) {
            const float4 a = *(const float4*)(wr + g * 8 + ks * 32);
            const float4 b = *(const float4*)(wr + g * 8 + ks * 32 + 4);
            wf[js][ks] = cvt8(a, b);
        }
        b1j[js] = b1[j];
        const float wz = wr[DD];
        const float w2 = W2[j];
        q0[js]  = w2;
        q1[js]  = w2 * wz;
        q2n[js] = -w2 * wz * wz;
        q3[js]  = w2 * wz * wz * wz;
    }
    const float b2s = b2[0];

    const int t0 = blockIdx.x * (TPB * TILE_T);

    float4 xa[4][2];
    auto issue_loads = [&](int tt) {
        const float* xr = X + (long long)(tt + r16) * DD + g * 8;
        #pragma unroll
        for (int ks = 0; ks < 4; ++ks) {
            xa[ks][0] = *(const float4*)(xr + ks * 32);
            xa[ks][1] = *(const float4*)(xr + ks * 32 + 4);
        }
    };

    issue_loads(t0);

    for (int tile = 0; tile < TPB; ++tile) {
        const int tt = t0 + tile * TILE_T;

        half8 xf[4];
        #pragma unroll
        for (int ks = 0; ks < 4; ++ks) xf[ks] = cvt8(xa[ks][0], xa[ks][1]);
        if (tile + 1 < TPB) issue_loads(tt + TILE_T);   // prefetch next tile

        f32x4 acc[4];
        #pragma unroll
        for (int js = 0; js < 4; ++js)
            acc[js] = f32x4{b1j[js], b1j[js], b1j[js], b1j[js]};
        #pragma unroll
        for (int js = 0; js < 4; ++js)
            #pragma unroll
            for (int ks = 0; ks < 4; ++ks)
                acc[js] = __builtin_amdgcn_mfma_f32_16x16x32_f16(
                    xf[ks], wf[js][ks], acc[js], 0, 0, 0);

        // postproc: element (t = tt + g*4 + r, j = jb + js*16 + r16)
        f32x4 c0 = {0,0,0,0}, c1 = {0,0,0,0}, c2 = {0,0,0,0}, c3 = {0,0,0,0};
        #pragma unroll
        for (int js = 0; js < 4; ++js) {
            #pragma unroll
            for (int r = 0; r < 4; ++r) {
                const float f  = fast_tanh(acc[js][r]);
                const float ff = f * f;
                const float d  = 1.0f - ff;
                const float fd = f * d;
                const float t3 = d * (ff - 0.3333333333f);
                c0[r] = fmaf(q0[js],  f,  c0[r]);
                c1[r] = fmaf(q1[js],  d,  c1[r]);
                c2[r] = fmaf(q2n[js], fd, c2[r]);
                c3[r] = fmaf(q3[js],  t3, c3[r]);
            }
        }
        #pragma unroll
        for (int r = 0; r < 4; ++r) {
            c0[r] = red16(c0[r]); c1[r] = red16(c1[r]);
            c2[r] = red16(c2[r]); c3[r] = red16(c3[r]);
        }
        if (r16 == 15) {
            #pragma unroll
            for (int r = 0; r < 4; ++r)
                redbuf[tile & 1][wid][g * 4 + r] =
                    make_float4(c0[r], c1[r], c2[r], c3[r]);
        }

        __syncthreads();   // redbuf[tile&1] visible; reuse fenced by next barrier

        if (tid < TILE_T) {
            const float4 a0 = redbuf[tile & 1][0][tid];
            const float4 a1 = redbuf[tile & 1][1][tid];
            const float4 a2 = redbuf[tile & 1][2][tid];
            const float4 a3 = redbuf[tile & 1][3][tid];
            float4 s;
            s.x = a0.x + a1.x + a2.x + a3.x + b2s;
            s.y = a0.y + a1.y + a2.y + a3.y;
            s.z = a0.z + a1.z + a2.z + a3.z;
            s.w = a0.w + a1.w + a2.w + a3.w;
            cs[tt + tid] = s;
        }
    }
}

// Phase 2: burn-in + scalar cubic chain; z's buffered in LDS, stores vectorized.
__global__ __launch_bounds__(64)
void chain_kernel(const float4* __restrict__ cs, float* __restrict__ out)
{
    const int c   = blockIdx.x;
    const int tid = threadIdx.x;
    const int s0     = (c == 0) ? 0 : c * P2_L - BURN;
    const int t_end  = min((c + 1) * P2_L, T_TOTAL - 1);
    const int n      = t_end - s0;
    const int wstart = c * P2_L;
    const int skip   = wstart - s0;          // 0 or BURN

    __shared__ float4 cl[P2_L + BURN];
    __shared__ float  zb[P2_L + BURN];
    for (int i = tid; i < n; i += 64) cl[i] = cs[s0 + i];
    __syncthreads();

    float z = 0.0f;
    #pragma unroll 4
    for (int i = 0; i < n; ++i) {
        const float4 k = cl[i];
        const float u = fmaf(fmaf(fmaf(k.w, z, k.z), z, k.y), z, k.x);
        z = fast_tanh(u);
        if (tid == 0) zb[i] = z;
    }
    __syncthreads();

    if (c == 0 && tid == 0) out[0] = 0.0f;
    for (int i = tid; i + skip < n; i += 64)
        out[wstart + 1 + i] = zb[skip + i];
}

extern "C" void kernel_launch(void* const* d_in, const int* in_sizes, int n_in,
                              void* d_out, int out_size, void* d_ws, size_t ws_size,
                              hipStream_t stream) {
    const float* X  = (const float*)d_in[0];
    const float* W1 = (const float*)d_in[1];
    const float* b1 = (const float*)d_in[2];
    const float* W2 = (const float*)d_in[3];
    const float* b2 = (const float*)d_in[4];
    float* out = (float*)d_out;
    float4* cs = (float4*)d_ws;        // 262144 * 16 B = 4 MiB scratch
    (void)in_sizes; (void)n_in; (void)out_size; (void)ws_size;

    coeff_kernel<<<P1_BLOCKS, 256, 0, stream>>>(X, W1, b1, W2, b2, cs);
    chain_kernel<<<P2_CHUNKS, 64, 0, stream>>>(cs, out);
}

// Round 6
// 110.035 us; speedup vs baseline: 1.1313x; 1.0517x over previous
//
#include <hip/hip_runtime.h>
#include <hip/hip_fp16.h>

#define T_TOTAL 262144
#define DD 128
#define HH 256

// ---- phase 1: coefficient GEMM ----
#define P1_BLOCKS 2048
#define TILE_T 16
#define TPB (T_TOTAL / TILE_T / P1_BLOCKS)   // 8 tiles per block
#define TBLK (TPB * TILE_T)                  // 128 t per block

// ---- phase 2: serial chain ----
#define P2_CHUNKS 2048
#define P2_L (T_TOTAL / P2_CHUNKS)   // 128
#define BURN 40

typedef _Float16 half8 __attribute__((ext_vector_type(8)));
typedef float f32x4 __attribute__((ext_vector_type(4)));

__device__ __forceinline__ float fast_tanh(float x) {
    float e = __expf(2.0f * x);
#if __has_builtin(__builtin_amdgcn_rcpf)
    float r = __builtin_amdgcn_rcpf(e + 1.0f);
#else
    float r = 1.0f / (e + 1.0f);
#endif
    return 1.0f - 2.0f * r;
}

template <int CTRL>
__device__ __forceinline__ float dpp_add(float x) {
    int t = __builtin_amdgcn_update_dpp(0, __float_as_int(x), CTRL, 0xf, 0xf, true);
    return x + __int_as_float(t);
}

// sum across the 16 lanes of each DPP row; lane (l&15)==15 holds the row sum
__device__ __forceinline__ float red16(float v) {
    v = dpp_add<0x111>(v);
    v = dpp_add<0x112>(v);
    v = dpp_add<0x114>(v);
    v = dpp_add<0x118>(v);
    return v;
}

__device__ __forceinline__ half8 cvt8(float4 a, float4 b) {
    half8 h;
    h[0] = (_Float16)a.x; h[1] = (_Float16)a.y;
    h[2] = (_Float16)a.z; h[3] = (_Float16)a.w;
    h[4] = (_Float16)b.x; h[5] = (_Float16)b.y;
    h[6] = (_Float16)b.z; h[7] = (_Float16)b.w;
    return h;
}

// Phase 1: per step t, cubic coefficients of u(z) = sum_j W2_j tanh(A[t][j] + wz_j z) + b2
//   c0 = sum W2 f ; c1 = sum W2 wz d ; c2 = -sum W2 wz^2 f d ;
//   c3 = sum W2 wz^3 d (f^2 - 1/3)     with f = tanh(A + b1), d = 1 - f^2.
// No barriers in the tile loop: each wave accumulates into its own LDS slab;
// one block-end reduce writes cs.
__global__ __launch_bounds__(256, 2)
void coeff_kernel(const float* __restrict__ X, const float* __restrict__ W1,
                  const float* __restrict__ b1, const float* __restrict__ W2,
                  const float* __restrict__ b2, float4* __restrict__ cs)
{
    const int tid = threadIdx.x;
    const int wid = tid >> 6;         // wave owns j in [64*wid, 64*wid+64)
    const int l   = tid & 63;
    const int r16 = l & 15;
    const int g   = l >> 4;
    const int jb  = wid * 64;

    __shared__ float4 slab[4][TBLK];   // per-wave partial coeffs, 8 KB

    // ---- permanent W fragments (B-operand): lane r16 <-> j, k = g*8 + ks*32 ----
    half8 wf[4][4];
    float b1j[4], q0[4], q1[4], q2n[4], q3[4];
    #pragma unroll
    for (int js = 0; js < 4; ++js) {
        const int j = jb + js * 16 + r16;
        const float* wr = W1 + j * (DD + 1);
        #pragma unroll
        for (int ks = 0; ks < 4; ++ks) {
            const float4 a = *(const float4*)(wr + g * 8 + ks * 32);
            const float4 b = *(const float4*)(wr + g * 8 + ks * 32 + 4);
            wf[js][ks] = cvt8(a, b);
        }
        b1j[js] = b1[j];
        const float wz = wr[DD];
        const float w2 = W2[j];
        q0[js]  = w2;
        q1[js]  = w2 * wz;
        q2n[js] = -w2 * wz * wz;
        q3[js]  = w2 * wz * wz * wz;
    }
    const float b2s = b2[0];

    const int t0 = blockIdx.x * TBLK;

    float4 xa[4][2];
    auto issue_loads = [&](int tt) {
        const float* xr = X + (long long)(tt + r16) * DD + g * 8;
        #pragma unroll
        for (int ks = 0; ks < 4; ++ks) {
            xa[ks][0] = *(const float4*)(xr + ks * 32);
            xa[ks][1] = *(const float4*)(xr + ks * 32 + 4);
        }
    };

    issue_loads(t0);

    for (int tile = 0; tile < TPB; ++tile) {
        const int tt = t0 + tile * TILE_T;

        half8 xf[4];
        #pragma unroll
        for (int ks = 0; ks < 4; ++ks) xf[ks] = cvt8(xa[ks][0], xa[ks][1]);
        if (tile + 1 < TPB) issue_loads(tt + TILE_T);   // prefetch next tile

        f32x4 acc[4];
        #pragma unroll
        for (int js = 0; js < 4; ++js)
            acc[js] = f32x4{b1j[js], b1j[js], b1j[js], b1j[js]};
        #pragma unroll
        for (int js = 0; js < 4; ++js)
            #pragma unroll
            for (int ks = 0; ks < 4; ++ks)
                acc[js] = __builtin_amdgcn_mfma_f32_16x16x32_f16(
                    xf[ks], wf[js][ks], acc[js], 0, 0, 0);

        // postproc: element (t = tt + g*4 + r, j = jb + js*16 + r16)
        f32x4 c0 = {0,0,0,0}, c1 = {0,0,0,0}, c2 = {0,0,0,0}, c3 = {0,0,0,0};
        #pragma unroll
        for (int js = 0; js < 4; ++js) {
            #pragma unroll
            for (int r = 0; r < 4; ++r) {
                const float f  = fast_tanh(acc[js][r]);
                const float ff = f * f;
                const float d  = 1.0f - ff;
                const float fd = f * d;
                const float t3 = d * (ff - 0.3333333333f);
                c0[r] = fmaf(q0[js],  f,  c0[r]);
                c1[r] = fmaf(q1[js],  d,  c1[r]);
                c2[r] = fmaf(q2n[js], fd, c2[r]);
                c3[r] = fmaf(q3[js],  t3, c3[r]);
            }
        }
        #pragma unroll
        for (int r = 0; r < 4; ++r) {
            c0[r] = red16(c0[r]); c1[r] = red16(c1[r]);
            c2[r] = red16(c2[r]); c3[r] = red16(c3[r]);
        }
        if (r16 == 15) {
            #pragma unroll
            for (int r = 0; r < 4; ++r)
                slab[wid][tile * TILE_T + g * 4 + r] =
                    make_float4(c0[r], c1[r], c2[r], c3[r]);
        }
        // no barrier: slabs are wave-private
    }

    __syncthreads();
    // block-end reduce: thread t sums the 4 wave slabs
    if (tid < TBLK) {
        const float4 a0 = slab[0][tid];
        const float4 a1 = slab[1][tid];
        const float4 a2 = slab[2][tid];
        const float4 a3 = slab[3][tid];
        float4 s;
        s.x = a0.x + a1.x + a2.x + a3.x + b2s;
        s.y = a0.y + a1.y + a2.y + a3.y;
        s.z = a0.z + a1.z + a2.z + a3.z;
        s.w = a0.w + a1.w + a2.w + a3.w;
        cs[t0 + tid] = s;
    }
}

// Phase 2: burn-in + scalar cubic chain; z's buffered in LDS, stores vectorized.
__global__ __launch_bounds__(64)
void chain_kernel(const float4* __restrict__ cs, float* __restrict__ out)
{
    const int c   = blockIdx.x;
    const int tid = threadIdx.x;
    const int s0     = (c == 0) ? 0 : c * P2_L - BURN;
    const int t_end  = min((c + 1) * P2_L, T_TOTAL - 1);
    const int n      = t_end - s0;
    const int wstart = c * P2_L;
    const int skip   = wstart - s0;          // 0 or BURN

    __shared__ float4 cl[P2_L + BURN];
    __shared__ float  zb[P2_L + BURN];
    for (int i = tid; i < n; i += 64) cl[i] = cs[s0 + i];
    __syncthreads();

    float z = 0.0f;
    #pragma unroll 4
    for (int i = 0; i < n; ++i) {
        const float4 k = cl[i];
        const float u = fmaf(fmaf(fmaf(k.w, z, k.z), z, k.y), z, k.x);
        z = fast_tanh(u);
        if (tid == 0) zb[i] = z;
    }
    __syncthreads();

    if (c == 0 && tid == 0) out[0] = 0.0f;
    for (int i = tid; i + skip < n; i += 64)
        out[wstart + 1 + i] = zb[skip + i];
}

extern "C" void kernel_launch(void* const* d_in, const int* in_sizes, int n_in,
                              void* d_out, int out_size, void* d_ws, size_t ws_size,
                              hipStream_t stream) {
    const float* X  = (const float*)d_in[0];
    const float* W1 = (const float*)d_in[1];
    const float* b1 = (const float*)d_in[2];
    const float* W2 = (const float*)d_in[3];
    const float* b2 = (const float*)d_in[4];
    float* out = (float*)d_out;
    float4* cs = (float4*)d_ws;        // 262144 * 16 B = 4 MiB scratch
    (void)in_sizes; (void)n_in; (void)out_size; (void)ws_size;

    coeff_kernel<<<P1_BLOCKS, 256, 0, stream>>>(X, W1, b1, W2, b2, cs);
    chain_kernel<<<P2_CHUNKS, 64, 0, stream>>>(cs, out);
}

// Round 8
// 94.622 us; speedup vs baseline: 1.3156x; 1.1629x over previous
//
#include <hip/hip_runtime.h>
#include <hip/hip_fp16.h>

#define T_TOTAL 262144
#define DD 128
#define HH 256

// ---- phase 1: coefficient GEMM ----
#define P1_BLOCKS 2048
#define TILE_T 16
#define TPB 8                         // tiles per block
#define TBLK (TPB * TILE_T)           // 128 t per block
#define XPITCH 132                    // f32 pitch: 528 B rows, 16B-aligned, padded
#define NW 8                          // waves per block

// ---- phase 2: serial chain ----
#define P2_CHUNKS 2048
#define P2_L (T_TOTAL / P2_CHUNKS)    // 128
#define BURN 40

typedef _Float16 half8 __attribute__((ext_vector_type(8)));
typedef __fp16 fp16x2 __attribute__((ext_vector_type(2)));
typedef unsigned int uint2v __attribute__((ext_vector_type(2)));
typedef float f32x4 __attribute__((ext_vector_type(4)));

__device__ __forceinline__ float fast_tanh(float x) {
    float e = __expf(2.0f * x);
#if __has_builtin(__builtin_amdgcn_rcpf)
    float r = __builtin_amdgcn_rcpf(e + 1.0f);
#else
    float r = 1.0f / (e + 1.0f);
#endif
    return 1.0f - 2.0f * r;
}

template <int CTRL>
__device__ __forceinline__ float dpp_add(float x) {
    int t = __builtin_amdgcn_update_dpp(0, __float_as_int(x), CTRL, 0xf, 0xf, true);
    return x + __int_as_float(t);
}

// sum across the 16 lanes of each DPP row; lane (l&15)==15 holds the row sum
__device__ __forceinline__ float red16(float v) {
    v = dpp_add<0x111>(v);
    v = dpp_add<0x112>(v);
    v = dpp_add<0x114>(v);
    v = dpp_add<0x118>(v);
    return v;
}

// RNE scalar pack (weights, loaded once)
__device__ __forceinline__ half8 cvt8(float4 a, float4 b) {
    half8 h;
    h[0] = (_Float16)a.x; h[1] = (_Float16)a.y;
    h[2] = (_Float16)a.z; h[3] = (_Float16)a.w;
    h[4] = (_Float16)b.x; h[5] = (_Float16)b.y;
    h[6] = (_Float16)b.z; h[7] = (_Float16)b.w;
    return h;
}

// fast packed RTZ conversion for X fragments (4 v_cvt_pkrtz instrs)
__device__ __forceinline__ half8 pack8(float4 a, float4 b) {
    const unsigned u0 = __builtin_bit_cast(unsigned, __builtin_amdgcn_cvt_pkrtz(a.x, a.y));
    const unsigned u1 = __builtin_bit_cast(unsigned, __builtin_amdgcn_cvt_pkrtz(a.z, a.w));
    const unsigned u2 = __builtin_bit_cast(unsigned, __builtin_amdgcn_cvt_pkrtz(b.x, b.y));
    const unsigned u3 = __builtin_bit_cast(unsigned, __builtin_amdgcn_cvt_pkrtz(b.z, b.w));
    unsigned int uv[4] = {u0, u1, u2, u3};
    return __builtin_bit_cast(half8, *(uint4*)uv);
}

// Phase 1: per step t, cubic coefficients of u(z) = sum_j W2_j tanh(A[t][j] + wz_j z) + b2
//   c0 = sum W2 f ; c1 = sum W2 wz d ; c2 = -sum W2 wz^2 f d ;
//   c3 = sum W2 wz^3 d (f^2 - 1/3)     with f = tanh(A + b1), d = 1 - f^2.
// 8 waves x 32 j each; X staged once per block into padded LDS (f32);
// per-wave partials in private slabs; one barrier per tile.
__global__ __launch_bounds__(512)
void coeff_kernel(const float* __restrict__ X, const float* __restrict__ W1,
                  const float* __restrict__ b1, const float* __restrict__ W2,
                  const float* __restrict__ b2, float4* __restrict__ cs)
{
    const int tid = threadIdx.x;
    const int wid = tid >> 6;         // wave 0..7 owns j in [32*wid, 32*wid+32)
    const int l   = tid & 63;
    const int r16 = l & 15;
    const int g   = l >> 4;
    const int jb  = wid * 32;

    __shared__ __align__(16) float xs[2][TILE_T][XPITCH];  // 16.5 KB x-tiles (f32)
    __shared__ float4 slab[NW][TBLK];                      // 16 KB per-wave partials

    // ---- permanent W fragments (B-operand): lane r16 <-> j, k = g*8 + ks*32 ----
    half8 wf[2][4];
    float b1j[2], q0[2], q1[2], q2n[2], q3[2];
    #pragma unroll
    for (int js = 0; js < 2; ++js) {
        const int j = jb + js * 16 + r16;
        const float* wr = W1 + j * (DD + 1);
        #pragma unroll
        for (int ks = 0; ks < 4; ++ks) {
            const float4 a = *(const float4*)(wr + g * 8 + ks * 32);
            const float4 b = *(const float4*)(wr + g * 8 + ks * 32 + 4);
            wf[js][ks] = cvt8(a, b);
        }
        b1j[js] = b1[j];
        const float wz = wr[DD];
        const float w2 = W2[j];
        q0[js]  = w2;
        q1[js]  = w2 * wz;
        q2n[js] = -w2 * wz * wz;
        q3[js]  = w2 * wz * wz * wz;
    }
    const float b2s = b2[0];

    const int t0 = blockIdx.x * TBLK;

    // ---- staging: wave wid stages rows [2*wid, 2*wid+2) of each tile ----
    const int srow = 2 * wid + (l >> 5);   // 0..15
    const int scol = (l & 31) * 4;         // f32 col, 16B per lane
    float4 sreg;
    auto ld_x = [&](int tt) {
        sreg = *(const float4*)(X + (long long)(tt + srow) * DD + scol);
    };
    auto st_x = [&](int buf) {
        *(float4*)&xs[buf][srow][scol] = sreg;
    };

    ld_x(t0);
    st_x(0);
    __syncthreads();

    for (int tile = 0; tile < TPB; ++tile) {
        if (tile + 1 < TPB) ld_x(t0 + (tile + 1) * TILE_T);   // async global load

        // MFMA: consume X fragments ks-by-ks from LDS
        f32x4 acc[2];
        #pragma unroll
        for (int js = 0; js < 2; ++js)
            acc[js] = f32x4{b1j[js], b1j[js], b1j[js], b1j[js]};
        #pragma unroll
        for (int ks = 0; ks < 4; ++ks) {
            const float* row = &xs[tile & 1][r16][g * 8 + ks * 32];
            const float4 a = *(const float4*)(row);
            const float4 b = *(const float4*)(row + 4);
            const half8 xf = pack8(a, b);
            acc[0] = __builtin_amdgcn_mfma_f32_16x16x32_f16(xf, wf[0][ks], acc[0], 0, 0, 0);
            acc[1] = __builtin_amdgcn_mfma_f32_16x16x32_f16(xf, wf[1][ks], acc[1], 0, 0, 0);
        }

        // postproc per r: element (t = t0 + tile*16 + g*4 + r, j = jb + js*16 + r16)
        #pragma unroll
        for (int r = 0; r < 4; ++r) {
            float c0 = 0.f, c1 = 0.f, c2 = 0.f, c3 = 0.f;
            #pragma unroll
            for (int js = 0; js < 2; ++js) {
                const float f  = fast_tanh(acc[js][r]);
                const float ff = f * f;
                const float d  = 1.0f - ff;
                const float fd = f * d;
                const float t3 = d * (ff - 0.3333333333f);
                c0 = fmaf(q0[js],  f,  c0);
                c1 = fmaf(q1[js],  d,  c1);
                c2 = fmaf(q2n[js], fd, c2);
                c3 = fmaf(q3[js],  t3, c3);
            }
            c0 = red16(c0); c1 = red16(c1); c2 = red16(c2); c3 = red16(c3);
            if (r16 == 15)
                slab[wid][tile * TILE_T + g * 4 + r] = make_float4(c0, c1, c2, c3);
        }

        if (tile + 1 < TPB) st_x((tile + 1) & 1);   // LDS write (vmcnt waited here)
        __syncthreads();
    }

    // block-end reduce: thread t sums the 8 wave slabs
    if (tid < TBLK) {
        float4 s = slab[0][tid];
        #pragma unroll
        for (int w = 1; w < NW; ++w) {
            const float4 a = slab[w][tid];
            s.x += a.x; s.y += a.y; s.z += a.z; s.w += a.w;
        }
        s.x += b2s;
        cs[t0 + tid] = s;
    }
}

// Phase 2: burn-in + scalar cubic chain; z's buffered in LDS, stores vectorized.
__global__ __launch_bounds__(64)
void chain_kernel(const float4* __restrict__ cs, float* __restrict__ out)
{
    const int c   = blockIdx.x;
    const int tid = threadIdx.x;
    const int s0     = (c == 0) ? 0 : c * P2_L - BURN;
    const int t_end  = min((c + 1) * P2_L, T_TOTAL - 1);
    const int n      = t_end - s0;
    const int wstart = c * P2_L;
    const int skip   = wstart - s0;          // 0 or BURN

    __shared__ float4 cl[P2_L + BURN];
    __shared__ float  zb[P2_L + BURN];
    for (int i = tid; i < n; i += 64) cl[i] = cs[s0 + i];
    __syncthreads();

    float z = 0.0f;
    #pragma unroll 4
    for (int i = 0; i < n; ++i) {
        const float4 k = cl[i];
        const float u = fmaf(fmaf(fmaf(k.w, z, k.z), z, k.y), z, k.x);
        z = fast_tanh(u);
        if (tid == 0) zb[i] = z;
    }
    __syncthreads();

    if (c == 0 && tid == 0) out[0] = 0.0f;
    for (int i = tid; i + skip < n; i += 64)
        out[wstart + 1 + i] = zb[skip + i];
}

extern "C" void kernel_launch(void* const* d_in, const int* in_sizes, int n_in,
                              void* d_out, int out_size, void* d_ws, size_t ws_size,
                              hipStream_t stream) {
    const float* X  = (const float*)d_in[0];
    const float* W1 = (const float*)d_in[1];
    const float* b1 = (const float*)d_in[2];
    const float* W2 = (const float*)d_in[3];
    const float* b2 = (const float*)d_in[4];
    float* out = (float*)d_out;
    float4* cs = (float4*)d_ws;        // 262144 * 16 B = 4 MiB scratch
    (void)in_sizes; (void)n_in; (void)out_size; (void)ws_size;

    coeff_kernel<<<P1_BLOCKS, 512, 0, stream>>>(X, W1, b1, W2, b2, cs);
    chain_kernel<<<P2_CHUNKS, 64, 0, stream>>>(cs, out);
}

// Round 10
// 85.252 us; speedup vs baseline: 1.4602x; 1.1099x over previous
//
#include <hip/hip_runtime.h>
#include <hip/hip_fp16.h>

#define T_TOTAL 262144
#define DD 128
#define HH 256

// ---- phase 1: coefficient GEMM ----
#define P1_BLOCKS 2048
#define TILE_T 16
#define TPB 8                         // tiles per block
#define TBLK (TPB * TILE_T)           // 128 t per block
#define NW 8                          // waves per block

// ---- phase 2: serial chain ----
#define P2_CHUNKS 2048
#define P2_L (T_TOTAL / P2_CHUNKS)    // 128
#define BURN 40

typedef _Float16 half8 __attribute__((ext_vector_type(8)));
typedef float f32x4 __attribute__((ext_vector_type(4)));

__device__ __forceinline__ float fast_tanh(float x) {
    float e = __expf(2.0f * x);
#if __has_builtin(__builtin_amdgcn_rcpf)
    float r = __builtin_amdgcn_rcpf(e + 1.0f);
#else
    float r = 1.0f / (e + 1.0f);
#endif
    return 1.0f - 2.0f * r;
}

template <int CTRL>
__device__ __forceinline__ float dpp_add(float x) {
    int t = __builtin_amdgcn_update_dpp(0, __float_as_int(x), CTRL, 0xf, 0xf, true);
    return x + __int_as_float(t);
}

// sum across the 16 lanes of each DPP row; lane (l&15)==15 holds the row sum
__device__ __forceinline__ float red16(float v) {
    v = dpp_add<0x111>(v);
    v = dpp_add<0x112>(v);
    v = dpp_add<0x114>(v);
    v = dpp_add<0x118>(v);
    return v;
}

// RNE scalar pack (weights, loaded once)
__device__ __forceinline__ half8 cvt8(float4 a, float4 b) {
    half8 h;
    h[0] = (_Float16)a.x; h[1] = (_Float16)a.y;
    h[2] = (_Float16)a.z; h[3] = (_Float16)a.w;
    h[4] = (_Float16)b.x; h[5] = (_Float16)b.y;
    h[6] = (_Float16)b.z; h[7] = (_Float16)b.w;
    return h;
}

// fast packed RTZ conversion (4 v_cvt_pkrtz) — used once per element at staging
__device__ __forceinline__ half8 pack8(float4 a, float4 b) {
    const unsigned u0 = __builtin_bit_cast(unsigned, __builtin_amdgcn_cvt_pkrtz(a.x, a.y));
    const unsigned u1 = __builtin_bit_cast(unsigned, __builtin_amdgcn_cvt_pkrtz(a.z, a.w));
    const unsigned u2 = __builtin_bit_cast(unsigned, __builtin_amdgcn_cvt_pkrtz(b.x, b.y));
    const unsigned u3 = __builtin_bit_cast(unsigned, __builtin_amdgcn_cvt_pkrtz(b.z, b.w));
    unsigned int uv[4] = {u0, u1, u2, u3};
    return __builtin_bit_cast(half8, *(uint4*)uv);
}

// Phase 1: per step t, cubic coefficients of u(z) = sum_j W2_j tanh(A[t][j] + wz_j z) + b2
//   c0 = sum W2 f ; c1 = sum W2 wz d ; c2 = -sum W2 wz^2 f d ;
//   c3 = sum W2 wz^3 d (f^2 - 1/3)     with f = tanh(A + b1), d = 1 - f^2.
// All X for the block staged ONCE as f16 into XOR-swizzled LDS (1 barrier);
// tile loop is barrier-free: ds_read_b128 fragments -> MFMA -> postproc -> slab.
__global__ __launch_bounds__(512)
void coeff_kernel(const float* __restrict__ X, const float* __restrict__ W1,
                  const float* __restrict__ b1, const float* __restrict__ W2,
                  const float* __restrict__ b2, float4* __restrict__ cs)
{
    const int tid = threadIdx.x;
    const int wid = tid >> 6;         // wave 0..7 owns j in [32*wid, 32*wid+32)
    const int l   = tid & 63;
    const int r16 = l & 15;
    const int g   = l >> 4;
    const int jb  = wid * 32;

    // X in f16, 16B-granule XOR swizzle: granule (row, gcol) lives at gcol^(row&7)
    __shared__ __align__(16) _Float16 xh[TBLK][DD];   // 32 KB
    __shared__ float4 slab[NW][TBLK];                 // 16 KB per-wave partials

    const int t0 = blockIdx.x * TBLK;

    // ---- stage all 128 rows of X (f32 -> f16, swizzled granules) ----
    // 128 rows x 16 granules (8 halves each) = 2048 granules; 512 threads x 4.
    {
        #pragma unroll
        for (int m = 0; m < 4; ++m) {
            const int G   = m * 512 + tid;        // granule id 0..2047
            const int row = G >> 4;               // 0..127
            const int gc  = (G & 15) ^ (row & 7); // swizzled granule col
            const float* src = X + (long long)(t0 + row) * DD + (G & 15) * 8;
            const float4 a = *(const float4*)(src);
            const float4 b = *(const float4*)(src + 4);
            *(half8*)&xh[row][gc * 8] = pack8(a, b);
        }
    }

    // ---- permanent W fragments (B-operand): lane r16 <-> j, k = g*8 + ks*32 ----
    half8 wf[2][4];
    float b1j[2], q0[2], q1[2], q2n[2], q3[2];
    #pragma unroll
    for (int js = 0; js < 2; ++js) {
        const int j = jb + js * 16 + r16;
        const float* wr = W1 + j * (DD + 1);
        #pragma unroll
        for (int ks = 0; ks < 4; ++ks) {
            const float4 a = *(const float4*)(wr + g * 8 + ks * 32);
            const float4 b = *(const float4*)(wr + g * 8 + ks * 32 + 4);
            wf[js][ks] = cvt8(a, b);
        }
        b1j[js] = b1[j];
        const float wz = wr[DD];
        const float w2 = W2[j];
        q0[js]  = w2;
        q1[js]  = w2 * wz;
        q2n[js] = -w2 * wz * wz;
        q3[js]  = w2 * wz * wz * wz;
    }
    const float b2s = b2[0];

    __syncthreads();   // the only barrier before the final reduce

    for (int tile = 0; tile < TPB; ++tile) {
        // fragments straight from swizzled LDS (1 x ds_read_b128 per ks)
        f32x4 acc[2];
        #pragma unroll
        for (int js = 0; js < 2; ++js)
            acc[js] = f32x4{b1j[js], b1j[js], b1j[js], b1j[js]};
        #pragma unroll
        for (int ks = 0; ks < 4; ++ks) {
            const int gc = (g + 4 * ks) ^ (r16 & 7);
            const half8 xf = *(const half8*)&xh[tile * TILE_T + r16][gc * 8];
            acc[0] = __builtin_amdgcn_mfma_f32_16x16x32_f16(xf, wf[0][ks], acc[0], 0, 0, 0);
            acc[1] = __builtin_amdgcn_mfma_f32_16x16x32_f16(xf, wf[1][ks], acc[1], 0, 0, 0);
        }

        // postproc per r: element (t = t0 + tile*16 + g*4 + r, j = jb + js*16 + r16)
        #pragma unroll
        for (int r = 0; r < 4; ++r) {
            float c0 = 0.f, c1 = 0.f, c2 = 0.f, c3 = 0.f;
            #pragma unroll
            for (int js = 0; js < 2; ++js) {
                const float f  = fast_tanh(acc[js][r]);
                const float ff = f * f;
                const float d  = 1.0f - ff;
                const float fd = f * d;
                const float t3 = d * (ff - 0.3333333333f);
                c0 = fmaf(q0[js],  f,  c0);
                c1 = fmaf(q1[js],  d,  c1);
                c2 = fmaf(q2n[js], fd, c2);
                c3 = fmaf(q3[js],  t3, c3);
            }
            c0 = red16(c0); c1 = red16(c1); c2 = red16(c2); c3 = red16(c3);
            if (r16 == 15)
                slab[wid][tile * TILE_T + g * 4 + r] = make_float4(c0, c1, c2, c3);
        }
    }

    __syncthreads();
    // block-end reduce: thread t sums the 8 wave slabs
    if (tid < TBLK) {
        float4 s = slab[0][tid];
        #pragma unroll
        for (int w = 1; w < NW; ++w) {
            const float4 a = slab[w][tid];
            s.x += a.x; s.y += a.y; s.z += a.z; s.w += a.w;
        }
        s.x += b2s;
        cs[t0 + tid] = s;
    }
}

// Phase 2: burn-in + scalar cubic chain; z's buffered in LDS, stores vectorized.
__global__ __launch_bounds__(64)
void chain_kernel(const float4* __restrict__ cs, float* __restrict__ out)
{
    const int c   = blockIdx.x;
    const int tid = threadIdx.x;
    const int s0     = (c == 0) ? 0 : c * P2_L - BURN;
    const int t_end  = min((c + 1) * P2_L, T_TOTAL - 1);
    const int n      = t_end - s0;
    const int wstart = c * P2_L;
    const int skip   = wstart - s0;          // 0 or BURN

    __shared__ float4 cl[P2_L + BURN];
    __shared__ float  zb[P2_L + BURN];
    for (int i = tid; i < n; i += 64) cl[i] = cs[s0 + i];
    __syncthreads();

    float z = 0.0f;
    #pragma unroll 4
    for (int i = 0; i < n; ++i) {
        const float4 k = cl[i];
        const float u = fmaf(fmaf(fmaf(k.w, z, k.z), z, k.y), z, k.x);
        z = fast_tanh(u);
        if (tid == 0) zb[i] = z;
    }
    __syncthreads();

    if (c == 0 && tid == 0) out[0] = 0.0f;
    for (int i = tid; i + skip < n; i += 64)
        out[wstart + 1 + i] = zb[skip + i];
}

extern "C" void kernel_launch(void* const* d_in, const int* in_sizes, int n_in,
                              void* d_out, int out_size, void* d_ws, size_t ws_size,
                              hipStream_t stream) {
    const float* X  = (const float*)d_in[0];
    const float* W1 = (const float*)d_in[1];
    const float* b1 = (const float*)d_in[2];
    const float* W2 = (const float*)d_in[3];
    const float* b2 = (const float*)d_in[4];
    float* out = (float*)d_out;
    float4* cs = (float4*)d_ws;        // 262144 * 16 B = 4 MiB scratch
    (void)in_sizes; (void)n_in; (void)out_size; (void)ws_size;

    coeff_kernel<<<P1_BLOCKS, 512, 0, stream>>>(X, W1, b1, W2, b2, cs);
    chain_kernel<<<P2_CHUNKS, 64, 0, stream>>>(cs, out);
}